// Round 1
// baseline (1621.599 us; speedup 1.0000x reference)
//
#include <hip/hip_runtime.h>
#include <hip/hip_bf16.h>
#include <stdint.h>

// Problem constants: B=2, T=2048, C=4096, H=32, hd=128; M=N=K=4096 for all GEMMs.
typedef __bf16 bf16_t;
typedef __attribute__((ext_vector_type(8))) __bf16 bf16x8;
typedef __attribute__((ext_vector_type(4))) float f32x4;

// async global->LDS, 16B/lane; LDS dest is wave-uniform base + lane*16 (m104).
#define GLL16(gptr, lptr)                                                      \
  __builtin_amdgcn_global_load_lds(                                            \
      (__attribute__((address_space(1))) void*)(gptr),                         \
      (__attribute__((address_space(3))) void*)(lptr), 16, 0, 0)

// ---------------- f32 -> bf16 cast, 8 elems/thread ----------------
__global__ __launch_bounds__(256) void cast_kernel(const float* __restrict__ in,
                                                   bf16_t* __restrict__ out,
                                                   int n8) {
  int i = blockIdx.x * 256 + threadIdx.x;
  if (i >= n8) return;
  const float4* p = (const float4*)in + (size_t)i * 2;
  float4 a = p[0], b = p[1];
  bf16x8 o;
  o[0] = (__bf16)a.x; o[1] = (__bf16)a.y; o[2] = (__bf16)a.z; o[3] = (__bf16)a.w;
  o[4] = (__bf16)b.x; o[5] = (__bf16)b.y; o[6] = (__bf16)b.z; o[7] = (__bf16)b.w;
  *((bf16x8*)out + i) = o;
}

// ---------------- RoPE (freqs all == 1.0 -> theta = t), in-place ----------------
__global__ __launch_bounds__(256) void rope_kernel(bf16_t* __restrict__ q,
                                                   bf16_t* __restrict__ k) {
  bf16_t* ptr = blockIdx.y ? k : q;
  int i = blockIdx.x * 256 + threadIdx.x;  // 8 elements = 4 pairs, same row
  int row = i >> 9;                        // (i*8)/4096
  float t = (float)(row & 2047);
  float fs, fc;
  sincosf(t, &fs, &fc);
  bf16x8 v = *((bf16x8*)ptr + i);
  bf16x8 o;
#pragma unroll
  for (int j = 0; j < 4; ++j) {
    float x0 = (float)v[2 * j], x1 = (float)v[2 * j + 1];
    o[2 * j]     = (__bf16)(x0 * fc - x1 * fs);
    o[2 * j + 1] = (__bf16)(x0 * fs + x1 * fc);
  }
  *((bf16x8*)ptr + i) = o;
}

// ---------------- NT GEMM: C[m,n] = sum_k A[m,k]*B[n,k], M=N=K=4096 ----------------
// MODE 0: bf16 C row-major. MODE 1: bf16 V stored transposed vt[((b*32+h)*128+d)*2048+t].
// MODE 2: f32 C row-major.
template <int MODE>
__global__ __launch_bounds__(256) void gemm_bt(const bf16_t* __restrict__ A,
                                               const bf16_t* __restrict__ B,
                                               void* __restrict__ Cout) {
  constexpr int K = 4096;
  __shared__ bf16_t As[128 * 32];
  __shared__ bf16_t Bs[128 * 32];
  const int tid = threadIdx.x;
  const int w = tid >> 6;
  const int lane = tid & 63;
  const int quad = lane >> 4;
  const int l15 = lane & 15;
  const int wr = w >> 1, wc = w & 1;
  const int bm = blockIdx.y * 128, bn = blockIdx.x * 128;

  // staging: 8 chunks of 1KB per matrix; wave w owns chunks {2w, 2w+1}
  const int c0 = w * 2, c1 = c0 + 1;
  const bf16_t* ga0 = A + (size_t)(bm + c0 * 16 + (lane >> 2)) * K + (lane & 3) * 8;
  const bf16_t* ga1 = A + (size_t)(bm + c1 * 16 + (lane >> 2)) * K + (lane & 3) * 8;
  const bf16_t* gb0 = B + (size_t)(bn + c0 * 16 + (lane >> 2)) * K + (lane & 3) * 8;
  const bf16_t* gb1 = B + (size_t)(bn + c1 * 16 + (lane >> 2)) * K + (lane & 3) * 8;
  bf16_t* la0 = &As[c0 * 512];
  bf16_t* la1 = &As[c1 * 512];
  bf16_t* lb0 = &Bs[c0 * 512];
  bf16_t* lb1 = &Bs[c1 * 512];

  f32x4 acc[4][4] = {};

  for (int k0 = 0; k0 < K; k0 += 32) {
    __syncthreads();
    GLL16(ga0 + k0, la0);
    GLL16(ga1 + k0, la1);
    GLL16(gb0 + k0, lb0);
    GLL16(gb1 + k0, lb1);
    __syncthreads();
    bf16x8 af[4], bfr[4];
#pragma unroll
    for (int mi = 0; mi < 4; ++mi)
      af[mi] = *(const bf16x8*)&As[(wr * 64 + mi * 16 + l15) * 32 + quad * 8];
#pragma unroll
    for (int ni = 0; ni < 4; ++ni)
      bfr[ni] = *(const bf16x8*)&Bs[(wc * 64 + ni * 16 + l15) * 32 + quad * 8];
#pragma unroll
    for (int mi = 0; mi < 4; ++mi)
#pragma unroll
      for (int ni = 0; ni < 4; ++ni)
        acc[mi][ni] = __builtin_amdgcn_mfma_f32_16x16x32_bf16(af[mi], bfr[ni],
                                                              acc[mi][ni], 0, 0, 0);
  }

#pragma unroll
  for (int mi = 0; mi < 4; ++mi) {
#pragma unroll
    for (int ni = 0; ni < 4; ++ni) {
      const int row0 = bm + wr * 64 + mi * 16 + quad * 4;  // C/D: row=quad*4+reg
      const int col = bn + wc * 64 + ni * 16 + l15;        // C/D: col=lane&15
      if constexpr (MODE == 0) {
        bf16_t* C = (bf16_t*)Cout;
#pragma unroll
        for (int r = 0; r < 4; ++r)
          C[(size_t)(row0 + r) * 4096 + col] = (__bf16)acc[mi][ni][r];
      } else if constexpr (MODE == 2) {
        float* C = (float*)Cout;
#pragma unroll
        for (int r = 0; r < 4; ++r)
          C[(size_t)(row0 + r) * 4096 + col] = acc[mi][ni][r];
      } else {
        // transposed V store: 4 consecutive t per lane -> one 8B store
        bf16_t* VT = (bf16_t*)Cout;
        const int b = row0 >> 11, t0 = row0 & 2047;
        const int h = col >> 7, d = col & 127;
        union { __bf16 e[4]; uint2 u; } pk;
#pragma unroll
        for (int r = 0; r < 4; ++r) pk.e[r] = (__bf16)acc[mi][ni][r];
        *(uint2*)&VT[((size_t)((b * 32 + h) * 128 + d)) * 2048 + t0] = pk.u;
      }
    }
  }
}

// ---------------- flash attention: 64x64 tiles, online softmax ----------------
// Q,K: [b*2048+t][h*128+d] bf16.  VT: [b,h][d][t] bf16.  O: same layout as Q.
__global__ __launch_bounds__(256) void attn_kernel(const bf16_t* __restrict__ Q,
                                                   const bf16_t* __restrict__ Km,
                                                   const bf16_t* __restrict__ VT,
                                                   bf16_t* __restrict__ O) {
  __shared__ bf16_t Qs[64 * 128];
  __shared__ bf16_t Ks[64 * 128];
  __shared__ bf16_t Vts[128 * 64];
  __shared__ bf16_t Ps[4][16 * 64];  // wave-private P staging
  const int tid = threadIdx.x;
  const int w = tid >> 6;
  const int lane = tid & 63;
  const int quad = lane >> 4;
  const int l15 = lane & 15;
  const int qtile = blockIdx.x;  // 0..31
  const int bh = blockIdx.y;     // 0..63
  const int mrow_base = (bh >> 5) * 2048;
  const int h = bh & 31;
  const float scale = 0.08838834764831845f;  // 128^-0.5

  // stage Q tile [64][128]; wave w owns chunks 4w..4w+3 (4 rows/chunk)
#pragma unroll
  for (int it = 0; it < 4; ++it) {
    int c = w * 4 + it;
    GLL16(Q + (size_t)(mrow_base + qtile * 64 + c * 4 + (lane >> 4)) * 4096 +
              h * 128 + l15 * 8,
          &Qs[c * 512]);
  }
  __syncthreads();
  bf16x8 qf[4];  // wave's 16 q-rows, full hd=128, kept in regs
#pragma unroll
  for (int ks = 0; ks < 4; ++ks)
    qf[ks] = *(const bf16x8*)&Qs[(w * 16 + l15) * 128 + ks * 32 + quad * 8];

  f32x4 accO[8] = {};
  float mrun[4], lrun[4];
#pragma unroll
  for (int r = 0; r < 4; ++r) { mrun[r] = -1e30f; lrun[r] = 0.f; }

  for (int kt = 0; kt <= qtile; ++kt) {
    __syncthreads();  // previous tile's LDS reads done
#pragma unroll
    for (int it = 0; it < 4; ++it) {
      int c = w * 4 + it;
      GLL16(Km + (size_t)(mrow_base + kt * 64 + c * 4 + (lane >> 4)) * 4096 +
                h * 128 + l15 * 8,
            &Ks[c * 512]);
      GLL16(VT + (size_t)(bh * 128 + c * 8 + (lane >> 3)) * 2048 + kt * 64 +
                (lane & 7) * 8,
            &Vts[c * 512]);
    }
    __syncthreads();

    // S = Q K^T for wave's 16 rows x 64 cols
    f32x4 s[4];
#pragma unroll
    for (int ni = 0; ni < 4; ++ni) {
      s[ni] = (f32x4){0.f, 0.f, 0.f, 0.f};
#pragma unroll
      for (int ks = 0; ks < 4; ++ks) {
        bf16x8 kf = *(const bf16x8*)&Ks[(ni * 16 + l15) * 128 + ks * 32 + quad * 8];
        s[ni] = __builtin_amdgcn_mfma_f32_16x16x32_bf16(qf[ks], kf, s[ni], 0, 0, 0);
      }
    }
    // scale + causal mask (only diagonal tile)
    const bool diag = (kt == qtile);
#pragma unroll
    for (int ni = 0; ni < 4; ++ni)
#pragma unroll
      for (int r = 0; r < 4; ++r) {
        float v = s[ni][r] * scale;
        if (diag && (ni * 16 + l15) > (w * 16 + quad * 4 + r)) v = -1e30f;
        s[ni][r] = v;
      }
    // online softmax
    float mx[4], alpha[4], rs[4];
#pragma unroll
    for (int r = 0; r < 4; ++r)
      mx[r] = fmaxf(fmaxf(s[0][r], s[1][r]), fmaxf(s[2][r], s[3][r]));
#pragma unroll
    for (int off = 1; off < 16; off <<= 1)
#pragma unroll
      for (int r = 0; r < 4; ++r) mx[r] = fmaxf(mx[r], __shfl_xor(mx[r], off, 64));
    float ps[4][4];
#pragma unroll
    for (int r = 0; r < 4; ++r) {
      float mn = fmaxf(mrun[r], mx[r]);
      alpha[r] = __expf(mrun[r] - mn);
      mrun[r] = mn;
      rs[r] = 0.f;
    }
#pragma unroll
    for (int ni = 0; ni < 4; ++ni)
#pragma unroll
      for (int r = 0; r < 4; ++r) {
        float p = __expf(s[ni][r] - mrun[r]);
        ps[ni][r] = p;
        rs[r] += p;
      }
#pragma unroll
    for (int off = 1; off < 16; off <<= 1)
#pragma unroll
      for (int r = 0; r < 4; ++r) rs[r] += __shfl_xor(rs[r], off, 64);
#pragma unroll
    for (int r = 0; r < 4; ++r) lrun[r] = lrun[r] * alpha[r] + rs[r];
#pragma unroll
    for (int nt = 0; nt < 8; ++nt)
#pragma unroll
      for (int r = 0; r < 4; ++r) accO[nt][r] *= alpha[r];
    // P: C-layout -> LDS -> A-operand layout (wave-private region)
#pragma unroll
    for (int ni = 0; ni < 4; ++ni)
#pragma unroll
      for (int r = 0; r < 4; ++r)
        Ps[w][(quad * 4 + r) * 64 + ni * 16 + l15] = (__bf16)ps[ni][r];
    __syncthreads();
    bf16x8 pf[2];
#pragma unroll
    for (int ks = 0; ks < 2; ++ks)
      pf[ks] = *(const bf16x8*)&Ps[w][l15 * 64 + ks * 32 + quad * 8];
#pragma unroll
    for (int nt = 0; nt < 8; ++nt)
#pragma unroll
      for (int ks = 0; ks < 2; ++ks) {
        bf16x8 vf = *(const bf16x8*)&Vts[(nt * 16 + l15) * 64 + ks * 32 + quad * 8];
        accO[nt] = __builtin_amdgcn_mfma_f32_16x16x32_bf16(pf[ks], vf, accO[nt], 0, 0, 0);
      }
  }

  // epilogue: O / l
#pragma unroll
  for (int r = 0; r < 4; ++r) lrun[r] = 1.f / lrun[r];
#pragma unroll
  for (int nt = 0; nt < 8; ++nt)
#pragma unroll
    for (int r = 0; r < 4; ++r) {
      int trow = qtile * 64 + w * 16 + quad * 4 + r;
      int d = nt * 16 + l15;
      O[(size_t)(mrow_base + trow) * 4096 + h * 128 + d] =
          (__bf16)(accO[nt][r] * lrun[r]);
    }
}

extern "C" void kernel_launch(void* const* d_in, const int* in_sizes, int n_in,
                              void* d_out, int out_size, void* d_ws, size_t ws_size,
                              hipStream_t stream) {
  (void)in_sizes; (void)n_in; (void)out_size; (void)ws_size;
  const float* x = (const float*)d_in[0];
  const float* wq = (const float*)d_in[1];
  const float* wk = (const float*)d_in[2];
  const float* wv = (const float*)d_in[3];
  const float* wo = (const float*)d_in[4];
  float* out = (float*)d_out;

  const size_t SZ = (size_t)4096 * 4096;  // 16M elems; 9 bf16 arrays = 288 MB ws
  bf16_t* xb = (bf16_t*)d_ws;
  bf16_t* wqb = xb + SZ;
  bf16_t* wkb = wqb + SZ;
  bf16_t* wvb = wkb + SZ;
  bf16_t* wob = wvb + SZ;
  bf16_t* qb = wob + SZ;
  bf16_t* kb = qb + SZ;
  bf16_t* vtb = kb + SZ;
  bf16_t* ab = vtb + SZ;

  const int n8 = (int)(SZ / 8);  // 2M threads, 8 elems each
  dim3 b256(256);
  cast_kernel<<<dim3(n8 / 256), b256, 0, stream>>>(x, xb, n8);
  cast_kernel<<<dim3(n8 / 256), b256, 0, stream>>>(wq, wqb, n8);
  cast_kernel<<<dim3(n8 / 256), b256, 0, stream>>>(wk, wkb, n8);
  cast_kernel<<<dim3(n8 / 256), b256, 0, stream>>>(wv, wvb, n8);
  cast_kernel<<<dim3(n8 / 256), b256, 0, stream>>>(wo, wob, n8);

  dim3 g(32, 32);
  gemm_bt<0><<<g, b256, 0, stream>>>(xb, wqb, qb);
  gemm_bt<0><<<g, b256, 0, stream>>>(xb, wkb, kb);
  gemm_bt<1><<<g, b256, 0, stream>>>(xb, wvb, vtb);

  rope_kernel<<<dim3(n8 / 256, 2), b256, 0, stream>>>(qb, kb);

  attn_kernel<<<dim3(32, 64), b256, 0, stream>>>(qb, kb, vtb, ab);

  gemm_bt<2><<<g, b256, 0, stream>>>(ab, wob, out);
}

// Round 2
// 1239.594 us; speedup vs baseline: 1.3082x; 1.3082x over previous
//
#include <hip/hip_runtime.h>
#include <hip/hip_bf16.h>
#include <stdint.h>

// Problem constants: B=2, T=2048, C=4096, H=32, hd=128; M=N=K=4096 for all GEMMs.
typedef __bf16 bf16_t;
typedef __attribute__((ext_vector_type(8))) __bf16 bf16x8;
typedef __attribute__((ext_vector_type(4))) float f32x4;

// async global->LDS, 16B/lane; LDS dest is wave-uniform base + lane*16 (m104).
#define GLL16(gptr, lptr)                                                      \
  __builtin_amdgcn_global_load_lds(                                            \
      (__attribute__((address_space(1))) void*)(gptr),                         \
      (__attribute__((address_space(3))) void*)(lptr), 16, 0, 0)

// ---------------- f32 -> bf16 cast, 8 elems/thread ----------------
__global__ __launch_bounds__(256) void cast_kernel(const float* __restrict__ in,
                                                   bf16_t* __restrict__ out,
                                                   int n8) {
  int i = blockIdx.x * 256 + threadIdx.x;
  if (i >= n8) return;
  const float4* p = (const float4*)in + (size_t)i * 2;
  float4 a = p[0], b = p[1];
  bf16x8 o;
  o[0] = (__bf16)a.x; o[1] = (__bf16)a.y; o[2] = (__bf16)a.z; o[3] = (__bf16)a.w;
  o[4] = (__bf16)b.x; o[5] = (__bf16)b.y; o[6] = (__bf16)b.z; o[7] = (__bf16)b.w;
  *((bf16x8*)out + i) = o;
}

// ---------------- NT GEMM: C[m,n] = sum_k A[m,k]*B[n,k], M=N=K=4096 ----------------
// MODE 0: bf16 C row-major.
// MODE 1: bf16 V stored transposed vt[((b*32+h)*128+d)*2048+t].
// MODE 2: f32 C row-major.
// MODE 3: bf16 C row-major with fused RoPE (theta = t, pairs = adjacent cols).
template <int MODE>
__global__ __launch_bounds__(256) void gemm_bt(const bf16_t* __restrict__ A,
                                               const bf16_t* __restrict__ B,
                                               void* __restrict__ Cout) {
  constexpr int K = 4096;
  __shared__ bf16_t As[128 * 32];
  __shared__ bf16_t Bs[128 * 32];
  const int tid = threadIdx.x;
  const int w = tid >> 6;
  const int lane = tid & 63;
  const int quad = lane >> 4;
  const int l15 = lane & 15;
  const int wr = w >> 1, wc = w & 1;
  const int bm = blockIdx.y * 128, bn = blockIdx.x * 128;

  // staging: 8 chunks of 1KB per matrix; wave w owns chunks {2w, 2w+1}
  const int c0 = w * 2, c1 = c0 + 1;
  const bf16_t* ga0 = A + (size_t)(bm + c0 * 16 + (lane >> 2)) * K + (lane & 3) * 8;
  const bf16_t* ga1 = A + (size_t)(bm + c1 * 16 + (lane >> 2)) * K + (lane & 3) * 8;
  const bf16_t* gb0 = B + (size_t)(bn + c0 * 16 + (lane >> 2)) * K + (lane & 3) * 8;
  const bf16_t* gb1 = B + (size_t)(bn + c1 * 16 + (lane >> 2)) * K + (lane & 3) * 8;
  bf16_t* la0 = &As[c0 * 512];
  bf16_t* la1 = &As[c1 * 512];
  bf16_t* lb0 = &Bs[c0 * 512];
  bf16_t* lb1 = &Bs[c1 * 512];

  f32x4 acc[4][4] = {};

  for (int k0 = 0; k0 < K; k0 += 32) {
    __syncthreads();
    GLL16(ga0 + k0, la0);
    GLL16(ga1 + k0, la1);
    GLL16(gb0 + k0, lb0);
    GLL16(gb1 + k0, lb1);
    __syncthreads();
    bf16x8 af[4], bfr[4];
#pragma unroll
    for (int mi = 0; mi < 4; ++mi)
      af[mi] = *(const bf16x8*)&As[(wr * 64 + mi * 16 + l15) * 32 + quad * 8];
#pragma unroll
    for (int ni = 0; ni < 4; ++ni)
      bfr[ni] = *(const bf16x8*)&Bs[(wc * 64 + ni * 16 + l15) * 32 + quad * 8];
#pragma unroll
    for (int mi = 0; mi < 4; ++mi)
#pragma unroll
      for (int ni = 0; ni < 4; ++ni)
        acc[mi][ni] = __builtin_amdgcn_mfma_f32_16x16x32_bf16(af[mi], bfr[ni],
                                                              acc[mi][ni], 0, 0, 0);
  }

#pragma unroll
  for (int mi = 0; mi < 4; ++mi) {
    const int row0 = bm + wr * 64 + mi * 16 + quad * 4;  // C/D: row=quad*4+reg
    float fsv[4], fcv[4];
    if constexpr (MODE == 3) {
#pragma unroll
      for (int r = 0; r < 4; ++r)
        sincosf((float)((row0 + r) & 2047), &fsv[r], &fcv[r]);
    }
#pragma unroll
    for (int ni = 0; ni < 4; ++ni) {
      const int col = bn + wc * 64 + ni * 16 + l15;  // C/D: col=lane&15
      if constexpr (MODE == 0) {
        bf16_t* C = (bf16_t*)Cout;
#pragma unroll
        for (int r = 0; r < 4; ++r)
          C[(size_t)(row0 + r) * 4096 + col] = (__bf16)acc[mi][ni][r];
      } else if constexpr (MODE == 2) {
        float* C = (float*)Cout;
#pragma unroll
        for (int r = 0; r < 4; ++r)
          C[(size_t)(row0 + r) * 4096 + col] = acc[mi][ni][r];
      } else if constexpr (MODE == 3) {
        bf16_t* C = (bf16_t*)Cout;
        const bool odd = (col & 1);
#pragma unroll
        for (int r = 0; r < 4; ++r) {
          float v = acc[mi][ni][r];
          float p = __shfl_xor(v, 1, 64);  // pair partner: adjacent col
          float o = odd ? (p * fsv[r] + v * fcv[r]) : (v * fcv[r] - p * fsv[r]);
          C[(size_t)(row0 + r) * 4096 + col] = (__bf16)o;
        }
      } else {
        // transposed V store: 4 consecutive t per lane -> one 8B store
        bf16_t* VT = (bf16_t*)Cout;
        const int b = row0 >> 11, t0 = row0 & 2047;
        const int h = col >> 7, d = col & 127;
        union { __bf16 e[4]; uint2 u; } pk;
#pragma unroll
        for (int r = 0; r < 4; ++r) pk.e[r] = (__bf16)acc[mi][ni][r];
        *(uint2*)&VT[((size_t)((b * 32 + h) * 128 + d)) * 2048 + t0] = pk.u;
      }
    }
  }
}

// ---------------- flash attention: 64x64 tiles, online softmax ----------------
// Q,K: [b*2048+t][h*128+d] bf16.  VT: [b,h][d][t] bf16.  O: same layout as Q.
// LDS swizzle: tile rows are 16 (K/Q) or 8 (V) chunks of 16B; chunk c of row r
// lives at slot c ^ (r & (nslots-1)). GLL16 dest must be contiguous, so the
// swizzle is applied to the per-lane GLOBAL address at staging time.
__global__ __launch_bounds__(256) void attn_kernel(const bf16_t* __restrict__ Q,
                                                   const bf16_t* __restrict__ Km,
                                                   const bf16_t* __restrict__ VT,
                                                   bf16_t* __restrict__ O) {
  __shared__ bf16_t Ks[64 * 128];    // 16 KB, swizzled
  __shared__ bf16_t Vts[128 * 64];   // 16 KB, swizzled
  __shared__ bf16_t QPs[64 * 128];   // 16 KB: Q staging, then P staging (reuse)
  const int tid = threadIdx.x;
  const int w = tid >> 6;
  const int lane = tid & 63;
  const int quad = lane >> 4;
  const int l15 = lane & 15;
  const int bh = blockIdx.x;             // 0..63
  const int qtile = 31 - blockIdx.y;     // heavy tiles first (load balance)
  const int mrow_base = (bh >> 5) * 2048;
  const int h = bh & 31;
  const float scale = 0.08838834764831845f;  // 128^-0.5

  // ---- stage Q tile [64][128], swizzled (16 slots/row) ----
#pragma unroll
  for (int it = 0; it < 4; ++it) {
    int c = w * 4 + it;                 // 1KB chunk-group = 4 rows
    int row = c * 4 + (lane >> 4);
    int cc = (lane & 15) ^ (row & 15);  // global chunk for this lane's slot
    GLL16(Q + (size_t)(mrow_base + qtile * 64 + row) * 4096 + h * 128 + cc * 8,
          &QPs[c * 512]);
  }
  __syncthreads();
  bf16x8 qf[4];  // wave's 16 q-rows, full hd=128, kept in regs
#pragma unroll
  for (int ks = 0; ks < 4; ++ks) {
    int row = w * 16 + l15;
    int slot = (ks * 4 + quad) ^ (row & 15);
    qf[ks] = *(const bf16x8*)&QPs[row * 128 + slot * 8];
  }
  // QPs is dead for Q now; reused for P staging (first loop barrier protects).
  bf16_t* Pw = &QPs[w * 16 * 72];  // wave-private P: 16 rows, stride 72 (pad)

  f32x4 accO[8] = {};
  float mrun[4], lrun[4];
#pragma unroll
  for (int r = 0; r < 4; ++r) { mrun[r] = -1e30f; lrun[r] = 0.f; }

  for (int kt = 0; kt <= qtile; ++kt) {
    __syncthreads();  // prev-iter LDS reads (and prologue Q reads) done
#pragma unroll
    for (int it = 0; it < 4; ++it) {
      int c = w * 4 + it;
      int krow = c * 4 + (lane >> 4);
      int kcc = (lane & 15) ^ (krow & 15);
      GLL16(Km + (size_t)(mrow_base + kt * 64 + krow) * 4096 + h * 128 + kcc * 8,
            &Ks[c * 512]);
      int vrow = c * 8 + (lane >> 3);
      int vcc = (lane & 7) ^ (vrow & 7);
      GLL16(VT + (size_t)(bh * 128 + vrow) * 2048 + kt * 64 + vcc * 8,
            &Vts[c * 512]);
    }
    __syncthreads();

    // S = Q K^T for wave's 16 rows x 64 cols
    f32x4 s[4];
#pragma unroll
    for (int ni = 0; ni < 4; ++ni) {
      s[ni] = (f32x4){0.f, 0.f, 0.f, 0.f};
#pragma unroll
      for (int ks = 0; ks < 4; ++ks) {
        int row = ni * 16 + l15;
        int slot = (ks * 4 + quad) ^ (row & 15);
        bf16x8 kf = *(const bf16x8*)&Ks[row * 128 + slot * 8];
        s[ni] = __builtin_amdgcn_mfma_f32_16x16x32_bf16(qf[ks], kf, s[ni], 0, 0, 0);
      }
    }
    // scale + causal mask (only diagonal tile)
    const bool diag = (kt == qtile);
#pragma unroll
    for (int ni = 0; ni < 4; ++ni)
#pragma unroll
      for (int r = 0; r < 4; ++r) {
        float v = s[ni][r] * scale;
        if (diag && (ni * 16 + l15) > (w * 16 + quad * 4 + r)) v = -1e30f;
        s[ni][r] = v;
      }
    // online softmax (row groups = 16 lanes)
    float mx[4], alpha[4], rs[4];
#pragma unroll
    for (int r = 0; r < 4; ++r)
      mx[r] = fmaxf(fmaxf(s[0][r], s[1][r]), fmaxf(s[2][r], s[3][r]));
#pragma unroll
    for (int off = 1; off < 16; off <<= 1)
#pragma unroll
      for (int r = 0; r < 4; ++r) mx[r] = fmaxf(mx[r], __shfl_xor(mx[r], off, 64));
    float ps[4][4];
#pragma unroll
    for (int r = 0; r < 4; ++r) {
      float mn = fmaxf(mrun[r], mx[r]);
      alpha[r] = __expf(mrun[r] - mn);
      mrun[r] = mn;
      rs[r] = 0.f;
    }
#pragma unroll
    for (int ni = 0; ni < 4; ++ni)
#pragma unroll
      for (int r = 0; r < 4; ++r) {
        float p = __expf(s[ni][r] - mrun[r]);
        ps[ni][r] = p;
        rs[r] += p;
      }
#pragma unroll
    for (int off = 1; off < 16; off <<= 1)
#pragma unroll
      for (int r = 0; r < 4; ++r) rs[r] += __shfl_xor(rs[r], off, 64);
#pragma unroll
    for (int r = 0; r < 4; ++r) lrun[r] = lrun[r] * alpha[r] + rs[r];
#pragma unroll
    for (int nt = 0; nt < 8; ++nt)
#pragma unroll
      for (int r = 0; r < 4; ++r) accO[nt][r] *= alpha[r];
    // P: C-layout -> wave-private LDS (padded stride 72) -> A-operand layout
#pragma unroll
    for (int ni = 0; ni < 4; ++ni)
#pragma unroll
      for (int r = 0; r < 4; ++r)
        Pw[(quad * 4 + r) * 72 + ni * 16 + l15] = (__bf16)ps[ni][r];
    // wave-private region: wave-local LDS drain suffices (no __syncthreads)
    asm volatile("s_waitcnt lgkmcnt(0)" ::: "memory");
    bf16x8 pf[2];
#pragma unroll
    for (int ks = 0; ks < 2; ++ks)
      pf[ks] = *(const bf16x8*)&Pw[l15 * 72 + ks * 32 + quad * 8];
#pragma unroll
    for (int nt = 0; nt < 8; ++nt)
#pragma unroll
      for (int ks = 0; ks < 2; ++ks) {
        int vrow = nt * 16 + l15;
        int slot = (ks * 4 + quad) ^ (vrow & 7);
        bf16x8 vf = *(const bf16x8*)&Vts[vrow * 64 + slot * 8];
        accO[nt] = __builtin_amdgcn_mfma_f32_16x16x32_bf16(pf[ks], vf, accO[nt], 0, 0, 0);
      }
  }

  // epilogue: O / l
#pragma unroll
  for (int r = 0; r < 4; ++r) lrun[r] = 1.f / lrun[r];
#pragma unroll
  for (int nt = 0; nt < 8; ++nt)
#pragma unroll
    for (int r = 0; r < 4; ++r) {
      int trow = qtile * 64 + w * 16 + quad * 4 + r;
      int d = nt * 16 + l15;
      O[(size_t)(mrow_base + trow) * 4096 + h * 128 + d] =
          (__bf16)(accO[nt][r] * lrun[r]);
    }
}

extern "C" void kernel_launch(void* const* d_in, const int* in_sizes, int n_in,
                              void* d_out, int out_size, void* d_ws, size_t ws_size,
                              hipStream_t stream) {
  (void)in_sizes; (void)n_in; (void)out_size; (void)ws_size;
  const float* x = (const float*)d_in[0];
  const float* wq = (const float*)d_in[1];
  const float* wk = (const float*)d_in[2];
  const float* wv = (const float*)d_in[3];
  const float* wo = (const float*)d_in[4];
  float* out = (float*)d_out;

  const size_t SZ = (size_t)4096 * 4096;  // 16M elems; 9 bf16 arrays = 288 MB ws
  bf16_t* xb = (bf16_t*)d_ws;
  bf16_t* wqb = xb + SZ;
  bf16_t* wkb = wqb + SZ;
  bf16_t* wvb = wkb + SZ;
  bf16_t* wob = wvb + SZ;
  bf16_t* qb = wob + SZ;
  bf16_t* kb = qb + SZ;
  bf16_t* vtb = kb + SZ;
  bf16_t* ab = vtb + SZ;

  const int n8 = (int)(SZ / 8);  // 2M threads, 8 elems each
  dim3 b256(256);
  cast_kernel<<<dim3(n8 / 256), b256, 0, stream>>>(x, xb, n8);
  cast_kernel<<<dim3(n8 / 256), b256, 0, stream>>>(wq, wqb, n8);
  cast_kernel<<<dim3(n8 / 256), b256, 0, stream>>>(wk, wkb, n8);
  cast_kernel<<<dim3(n8 / 256), b256, 0, stream>>>(wv, wvb, n8);
  cast_kernel<<<dim3(n8 / 256), b256, 0, stream>>>(wo, wob, n8);

  dim3 g(32, 32);
  gemm_bt<3><<<g, b256, 0, stream>>>(xb, wqb, qb);   // Q proj + RoPE
  gemm_bt<3><<<g, b256, 0, stream>>>(xb, wkb, kb);   // K proj + RoPE
  gemm_bt<1><<<g, b256, 0, stream>>>(xb, wvb, vtb);  // V proj, transposed store

  attn_kernel<<<dim3(64, 32), b256, 0, stream>>>(qb, kb, vtb, ab);

  gemm_bt<2><<<g, b256, 0, stream>>>(ab, wob, out);
}

// Round 3
// 1218.659 us; speedup vs baseline: 1.3306x; 1.0172x over previous
//
#include <hip/hip_runtime.h>
#include <hip/hip_bf16.h>
#include <stdint.h>

// Problem constants: B=2, T=2048, C=4096, H=32, hd=128; M=N=K=4096 for all GEMMs.
typedef __bf16 bf16_t;
typedef __attribute__((ext_vector_type(8))) __bf16 bf16x8;
typedef __attribute__((ext_vector_type(4))) float f32x4;

// async global->LDS, 16B/lane; LDS dest is wave-uniform base + lane*16 (m104).
#define GLL16(gptr, lptr)                                                      \
  __builtin_amdgcn_global_load_lds(                                            \
      (__attribute__((address_space(1))) void*)(gptr),                         \
      (__attribute__((address_space(3))) void*)(lptr), 16, 0, 0)

// ---------------- fused f32 -> bf16 cast for all 5 tensors ----------------
// Outputs are CONTIGUOUS in ws: xb,wqb,wkb,wvb,wob. Input picked by blockIdx.y.
__global__ __launch_bounds__(256) void cast5_kernel(const float* __restrict__ x,
                                                    const float* __restrict__ wq,
                                                    const float* __restrict__ wk,
                                                    const float* __restrict__ wv,
                                                    const float* __restrict__ wo,
                                                    bf16_t* __restrict__ outbase) {
  const size_t SZ = (size_t)4096 * 4096;
  const float* in;
  switch (blockIdx.y) {
    case 0: in = x; break;
    case 1: in = wq; break;
    case 2: in = wk; break;
    case 3: in = wv; break;
    default: in = wo; break;
  }
  bf16_t* out = outbase + (size_t)blockIdx.y * SZ;
  int i = blockIdx.x * 256 + threadIdx.x;  // 8 elems/thread
  const float4* p = (const float4*)in + (size_t)i * 2;
  float4 a = p[0], b = p[1];
  bf16x8 o;
  o[0] = (__bf16)a.x; o[1] = (__bf16)a.y; o[2] = (__bf16)a.z; o[3] = (__bf16)a.w;
  o[4] = (__bf16)b.x; o[5] = (__bf16)b.y; o[6] = (__bf16)b.z; o[7] = (__bf16)b.w;
  *((bf16x8*)out + i) = o;
}

// ---------------- GEMM epilogue helpers ----------------
// C/D fragment mapping (16x16x32): row = quad*4 + reg, col = lane&15.
__device__ __forceinline__ void epi_rope(f32x4 acc[4][4], bf16_t* C, int bm,
                                         int bn, int wr, int wc, int quad,
                                         int l15) {
#pragma unroll
  for (int mi = 0; mi < 4; ++mi) {
    const int row0 = bm + wr * 64 + mi * 16 + quad * 4;
    float fsv[4], fcv[4];
#pragma unroll
    for (int r = 0; r < 4; ++r)
      sincosf((float)((row0 + r) & 2047), &fsv[r], &fcv[r]);
#pragma unroll
    for (int ni = 0; ni < 4; ++ni) {
      const int col = bn + wc * 64 + ni * 16 + l15;
      const bool odd = (col & 1);
#pragma unroll
      for (int r = 0; r < 4; ++r) {
        float v = acc[mi][ni][r];
        float p = __shfl_xor(v, 1, 64);  // RoPE pair partner: adjacent col
        float o = odd ? (p * fsv[r] + v * fcv[r]) : (v * fcv[r] - p * fsv[r]);
        C[(size_t)(row0 + r) * 4096 + col] = (__bf16)o;
      }
    }
  }
}

__device__ __forceinline__ void epi_vt(f32x4 acc[4][4], bf16_t* VT, int bm,
                                       int bn, int wr, int wc, int quad,
                                       int l15) {
#pragma unroll
  for (int mi = 0; mi < 4; ++mi) {
    const int row0 = bm + wr * 64 + mi * 16 + quad * 4;
    const int b = row0 >> 11, t0 = row0 & 2047;
#pragma unroll
    for (int ni = 0; ni < 4; ++ni) {
      const int col = bn + wc * 64 + ni * 16 + l15;
      const int h = col >> 7, d = col & 127;
      union { __bf16 e[4]; uint2 u; } pk;
#pragma unroll
      for (int r = 0; r < 4; ++r) pk.e[r] = (__bf16)acc[mi][ni][r];
      *(uint2*)&VT[((size_t)((b * 32 + h) * 128 + d)) * 2048 + t0] = pk.u;
    }
  }
}

// ---------------- ping-pong NT GEMM main loop (shared by both kernels) -------
// Stages A/B 128x32 tiles into double-buffered LDS; GLL for tile k+1 issued
// before compute on tile k (single barrier per iter -> latency overlapped).
// LDS granule swizzle: 16B granule g of row r stored at slot g ^ (r&3)
// (applied on the GLOBAL address side; GLL16 dest must stay contiguous).
#define GEMM_MAIN_LOOP(Aptr, Bptr)                                             \
  const int c0 = w * 2, c1 = c0 + 1;                                           \
  const int ra = lane >> 2;                                                    \
  const int gsw = ((lane & 3) ^ (ra & 3)) * 8;                                 \
  const bf16_t* ga0 = Aptr + (size_t)(bm + c0 * 16 + ra) * 4096 + gsw;         \
  const bf16_t* ga1 = Aptr + (size_t)(bm + c1 * 16 + ra) * 4096 + gsw;         \
  const bf16_t* gb0 = Bptr + (size_t)(bn + c0 * 16 + ra) * 4096 + gsw;         \
  const bf16_t* gb1 = Bptr + (size_t)(bn + c1 * 16 + ra) * 4096 + gsw;         \
  f32x4 acc[4][4] = {};                                                        \
  GLL16(ga0, &As[0][c0 * 512]);                                                \
  GLL16(ga1, &As[0][c1 * 512]);                                                \
  GLL16(gb0, &Bs[0][c0 * 512]);                                                \
  GLL16(gb1, &Bs[0][c1 * 512]);                                                \
  const int sa = quad ^ (l15 & 3); /* frag slot swizzle */                     \
  for (int kt = 0; kt < 128; ++kt) {                                           \
    const int p = kt & 1;                                                      \
    __syncthreads(); /* drains GLL for buf p; protects buf p^1 overwrite */    \
    if (kt != 127) {                                                           \
      const int k1 = (kt + 1) * 32;                                            \
      GLL16(ga0 + k1, &As[p ^ 1][c0 * 512]);                                   \
      GLL16(ga1 + k1, &As[p ^ 1][c1 * 512]);                                   \
      GLL16(gb0 + k1, &Bs[p ^ 1][c0 * 512]);                                   \
      GLL16(gb1 + k1, &Bs[p ^ 1][c1 * 512]);                                   \
    }                                                                          \
    bf16x8 af[4], bfr[4];                                                      \
    _Pragma("unroll") for (int mi = 0; mi < 4; ++mi)                           \
        af[mi] = *(const bf16x8*)&As[p][(wr * 64 + mi * 16 + l15) * 32 + sa * 8]; \
    _Pragma("unroll") for (int ni = 0; ni < 4; ++ni)                           \
        bfr[ni] = *(const bf16x8*)&Bs[p][(wc * 64 + ni * 16 + l15) * 32 + sa * 8]; \
    _Pragma("unroll") for (int mi = 0; mi < 4; ++mi)                           \
        _Pragma("unroll") for (int ni = 0; ni < 4; ++ni)                       \
            acc[mi][ni] = __builtin_amdgcn_mfma_f32_16x16x32_bf16(              \
                af[mi], bfr[ni], acc[mi][ni], 0, 0, 0);                        \
  }

// ---------------- fused QKV projection: grid (96, 32) ----------------
// blockIdx.x>>5 selects matrix: 0=Q (RoPE), 1=K (RoPE), 2=V (transposed store).
__global__ __launch_bounds__(256) void gemm_qkv(const bf16_t* __restrict__ X,
                                                const bf16_t* __restrict__ WQ,
                                                const bf16_t* __restrict__ WK,
                                                const bf16_t* __restrict__ WV,
                                                bf16_t* __restrict__ Qo,
                                                bf16_t* __restrict__ Ko,
                                                bf16_t* __restrict__ VTo) {
  __shared__ bf16_t As[2][128 * 32];
  __shared__ bf16_t Bs[2][128 * 32];
  const int tid = threadIdx.x;
  const int w = tid >> 6;
  const int lane = tid & 63;
  const int quad = lane >> 4;
  const int l15 = lane & 15;
  const int wr = w >> 1, wc = w & 1;
  const int mat = blockIdx.x >> 5;
  const int bn = (blockIdx.x & 31) * 128, bm = blockIdx.y * 128;
  const bf16_t* Bp = (mat == 0) ? WQ : (mat == 1) ? WK : WV;

  GEMM_MAIN_LOOP(X, Bp)

  if (mat == 0)
    epi_rope(acc, Qo, bm, bn, wr, wc, quad, l15);
  else if (mat == 1)
    epi_rope(acc, Ko, bm, bn, wr, wc, quad, l15);
  else
    epi_vt(acc, VTo, bm, bn, wr, wc, quad, l15);
}

// ---------------- output projection GEMM: f32 C row-major ----------------
__global__ __launch_bounds__(256) void gemm_out(const bf16_t* __restrict__ A,
                                                const bf16_t* __restrict__ B,
                                                float* __restrict__ C) {
  __shared__ bf16_t As[2][128 * 32];
  __shared__ bf16_t Bs[2][128 * 32];
  const int tid = threadIdx.x;
  const int w = tid >> 6;
  const int lane = tid & 63;
  const int quad = lane >> 4;
  const int l15 = lane & 15;
  const int wr = w >> 1, wc = w & 1;
  const int bn = blockIdx.x * 128, bm = blockIdx.y * 128;

  GEMM_MAIN_LOOP(A, B)

#pragma unroll
  for (int mi = 0; mi < 4; ++mi) {
    const int row0 = bm + wr * 64 + mi * 16 + quad * 4;
#pragma unroll
    for (int ni = 0; ni < 4; ++ni) {
      const int col = bn + wc * 64 + ni * 16 + l15;
#pragma unroll
      for (int r = 0; r < 4; ++r)
        C[(size_t)(row0 + r) * 4096 + col] = acc[mi][ni][r];
    }
  }
}

// ---------------- flash attention: 64x64 tiles, online softmax ----------------
// Q,K: [b*2048+t][h*128+d] bf16.  VT: [b,h][d][t] bf16.  O: same layout as Q.
// LDS swizzle: chunk c of row r lives at slot c ^ (r & (nslots-1)); swizzle is
// applied to the per-lane GLOBAL address at staging time (GLL16 dest contiguous).
__global__ __launch_bounds__(256) void attn_kernel(const bf16_t* __restrict__ Q,
                                                   const bf16_t* __restrict__ Km,
                                                   const bf16_t* __restrict__ VT,
                                                   bf16_t* __restrict__ O) {
  __shared__ bf16_t Ks[64 * 128];    // 16 KB, swizzled
  __shared__ bf16_t Vts[128 * 64];   // 16 KB, swizzled
  __shared__ bf16_t QPs[64 * 128];   // 16 KB: Q staging, then P staging (reuse)
  const int tid = threadIdx.x;
  const int w = tid >> 6;
  const int lane = tid & 63;
  const int quad = lane >> 4;
  const int l15 = lane & 15;
  const int bh = blockIdx.x;             // 0..63
  const int qtile = 31 - blockIdx.y;     // heavy tiles first (load balance)
  const int mrow_base = (bh >> 5) * 2048;
  const int h = bh & 31;
  const float scale = 0.08838834764831845f;  // 128^-0.5

  // ---- stage Q tile [64][128], swizzled (16 slots/row) ----
#pragma unroll
  for (int it = 0; it < 4; ++it) {
    int c = w * 4 + it;                 // 1KB chunk-group = 4 rows
    int row = c * 4 + (lane >> 4);
    int cc = (lane & 15) ^ (row & 15);  // global chunk for this lane's slot
    GLL16(Q + (size_t)(mrow_base + qtile * 64 + row) * 4096 + h * 128 + cc * 8,
          &QPs[c * 512]);
  }
  __syncthreads();
  bf16x8 qf[4];  // wave's 16 q-rows, full hd=128, kept in regs
#pragma unroll
  for (int ks = 0; ks < 4; ++ks) {
    int row = w * 16 + l15;
    int slot = (ks * 4 + quad) ^ (row & 15);
    qf[ks] = *(const bf16x8*)&QPs[row * 128 + slot * 8];
  }
  // QPs is dead for Q now; reused for P staging (first loop barrier protects).
  bf16_t* Pw = &QPs[w * 16 * 72];  // wave-private P: 16 rows, stride 72 (pad)

  f32x4 accO[8] = {};
  float mrun[4], lrun[4];
#pragma unroll
  for (int r = 0; r < 4; ++r) { mrun[r] = -1e30f; lrun[r] = 0.f; }

  for (int kt = 0; kt <= qtile; ++kt) {
    __syncthreads();  // prev-iter LDS reads (and prologue Q reads) done
#pragma unroll
    for (int it = 0; it < 4; ++it) {
      int c = w * 4 + it;
      int krow = c * 4 + (lane >> 4);
      int kcc = (lane & 15) ^ (krow & 15);
      GLL16(Km + (size_t)(mrow_base + kt * 64 + krow) * 4096 + h * 128 + kcc * 8,
            &Ks[c * 512]);
      int vrow = c * 8 + (lane >> 3);
      int vcc = (lane & 7) ^ (vrow & 7);
      GLL16(VT + (size_t)(bh * 128 + vrow) * 2048 + kt * 64 + vcc * 8,
            &Vts[c * 512]);
    }
    __syncthreads();

    // S = Q K^T for wave's 16 rows x 64 cols
    f32x4 s[4];
#pragma unroll
    for (int ni = 0; ni < 4; ++ni) {
      s[ni] = (f32x4){0.f, 0.f, 0.f, 0.f};
#pragma unroll
      for (int ks = 0; ks < 4; ++ks) {
        int row = ni * 16 + l15;
        int slot = (ks * 4 + quad) ^ (row & 15);
        bf16x8 kf = *(const bf16x8*)&Ks[row * 128 + slot * 8];
        s[ni] = __builtin_amdgcn_mfma_f32_16x16x32_bf16(qf[ks], kf, s[ni], 0, 0, 0);
      }
    }
    // scale + causal mask (only diagonal tile)
    const bool diag = (kt == qtile);
#pragma unroll
    for (int ni = 0; ni < 4; ++ni)
#pragma unroll
      for (int r = 0; r < 4; ++r) {
        float v = s[ni][r] * scale;
        if (diag && (ni * 16 + l15) > (w * 16 + quad * 4 + r)) v = -1e30f;
        s[ni][r] = v;
      }
    // online softmax (row groups = 16 lanes)
    float mx[4], alpha[4], rs[4];
#pragma unroll
    for (int r = 0; r < 4; ++r)
      mx[r] = fmaxf(fmaxf(s[0][r], s[1][r]), fmaxf(s[2][r], s[3][r]));
#pragma unroll
    for (int off = 1; off < 16; off <<= 1)
#pragma unroll
      for (int r = 0; r < 4; ++r) mx[r] = fmaxf(mx[r], __shfl_xor(mx[r], off, 64));
    float ps[4][4];
#pragma unroll
    for (int r = 0; r < 4; ++r) {
      float mn = fmaxf(mrun[r], mx[r]);
      alpha[r] = __expf(mrun[r] - mn);
      mrun[r] = mn;
      rs[r] = 0.f;
    }
#pragma unroll
    for (int ni = 0; ni < 4; ++ni)
#pragma unroll
      for (int r = 0; r < 4; ++r) {
        float p = __expf(s[ni][r] - mrun[r]);
        ps[ni][r] = p;
        rs[r] += p;
      }
#pragma unroll
    for (int off = 1; off < 16; off <<= 1)
#pragma unroll
      for (int r = 0; r < 4; ++r) rs[r] += __shfl_xor(rs[r], off, 64);
#pragma unroll
    for (int r = 0; r < 4; ++r) lrun[r] = lrun[r] * alpha[r] + rs[r];
#pragma unroll
    for (int nt = 0; nt < 8; ++nt)
#pragma unroll
      for (int r = 0; r < 4; ++r) accO[nt][r] *= alpha[r];
    // P: C-layout -> wave-private LDS (padded stride 72) -> A-operand layout
#pragma unroll
    for (int ni = 0; ni < 4; ++ni)
#pragma unroll
      for (int r = 0; r < 4; ++r)
        Pw[(quad * 4 + r) * 72 + ni * 16 + l15] = (__bf16)ps[ni][r];
    // wave-private region: wave-local LDS drain suffices (no __syncthreads)
    asm volatile("s_waitcnt lgkmcnt(0)" ::: "memory");
    bf16x8 pf[2];
#pragma unroll
    for (int ks = 0; ks < 2; ++ks)
      pf[ks] = *(const bf16x8*)&Pw[l15 * 72 + ks * 32 + quad * 8];
#pragma unroll
    for (int nt = 0; nt < 8; ++nt)
#pragma unroll
      for (int ks = 0; ks < 2; ++ks) {
        int vrow = nt * 16 + l15;
        int slot = (ks * 4 + quad) ^ (vrow & 7);
        bf16x8 vf = *(const bf16x8*)&Vts[vrow * 64 + slot * 8];
        accO[nt] = __builtin_amdgcn_mfma_f32_16x16x32_bf16(pf[ks], vf, accO[nt], 0, 0, 0);
      }
  }

  // epilogue: O / l
#pragma unroll
  for (int r = 0; r < 4; ++r) lrun[r] = 1.f / lrun[r];
#pragma unroll
  for (int nt = 0; nt < 8; ++nt)
#pragma unroll
    for (int r = 0; r < 4; ++r) {
      int trow = qtile * 64 + w * 16 + quad * 4 + r;
      int d = nt * 16 + l15;
      O[(size_t)(mrow_base + trow) * 4096 + h * 128 + d] =
          (__bf16)(accO[nt][r] * lrun[r]);
    }
}

extern "C" void kernel_launch(void* const* d_in, const int* in_sizes, int n_in,
                              void* d_out, int out_size, void* d_ws, size_t ws_size,
                              hipStream_t stream) {
  (void)in_sizes; (void)n_in; (void)out_size; (void)ws_size;
  const float* x = (const float*)d_in[0];
  const float* wq = (const float*)d_in[1];
  const float* wk = (const float*)d_in[2];
  const float* wv = (const float*)d_in[3];
  const float* wo = (const float*)d_in[4];
  float* out = (float*)d_out;

  const size_t SZ = (size_t)4096 * 4096;  // 16M elems; 9 bf16 arrays = 288 MB ws
  bf16_t* xb = (bf16_t*)d_ws;
  bf16_t* wqb = xb + SZ;
  bf16_t* wkb = wqb + SZ;
  bf16_t* wvb = wkb + SZ;
  bf16_t* wob = wvb + SZ;
  bf16_t* qb = wob + SZ;
  bf16_t* kb = qb + SZ;
  bf16_t* vtb = kb + SZ;
  bf16_t* ab = vtb + SZ;

  dim3 b256(256);
  cast5_kernel<<<dim3((unsigned)(SZ / 8 / 256), 5), b256, 0, stream>>>(
      x, wq, wk, wv, wo, xb);

  gemm_qkv<<<dim3(96, 32), b256, 0, stream>>>(xb, wqb, wkb, wvb, qb, kb, vtb);

  attn_kernel<<<dim3(64, 32), b256, 0, stream>>>(qb, kb, vtb, ab);

  gemm_out<<<dim3(32, 32), b256, 0, stream>>>(ab, wob, out);
}